// Round 9
// baseline (290.248 us; speedup 1.0000x reference)
//
#include <hip/hip_runtime.h>
#include <hip/hip_bf16.h>

typedef __bf16 bf16x8_t __attribute__((ext_vector_type(8)));
typedef __bf16 bf16x4_t __attribute__((ext_vector_type(4)));
typedef float  f32x4_t  __attribute__((ext_vector_type(4)));

#define MFMA_16x16x32_BF16(A, B, C) __builtin_amdgcn_mfma_f32_16x16x32_bf16((A), (B), (C), 0, 0, 0)

static constexpr int B_ = 16;
static constexpr int T_ = 2048;
static constexpr int C_ = 1024;
static constexpr int H_ = 128;
static constexpr long M_ = (long)B_ * T_;   // 32768 rows

__device__ __forceinline__ void gload_lds16(const void* g, void* l)
{
    __builtin_amdgcn_global_load_lds(
        (const __attribute__((address_space(1))) void*)g,
        (__attribute__((address_space(3))) void*)l, 16, 0, 0);
}

// ---------------------------------------------------------------------------
// W fragment-linear pack: WB[nt][t][lane][8] bf16, nt=n-tile 0..23 (z=nt>>3,
// within-tile col m16 -> h=(nt&7)*16+m16), t=k-step 0..31, lane=quad*16+m16,
// elems e=0..7 -> W_z[c = t*32+quad*8+e][h].  A wave's MFMA B-fragment for
// (nt,t) is then ONE contiguous 1 KB block. Total 768 KB, L2-resident.
// ---------------------------------------------------------------------------
__global__ __launch_bounds__(256) void wt_kernel(
    const float* __restrict__ Wq, const float* __restrict__ Wk,
    const float* __restrict__ Wv, __bf16* __restrict__ WB)
{
    const int pair = blockIdx.x * 4 + (threadIdx.x >> 6);   // 0..767 = nt*32+t
    const int lane = threadIdx.x & 63;
    const int m16  = lane & 15;
    const int quad = lane >> 4;
    const int nt   = pair >> 5;
    const int t    = pair & 31;
    const int z    = nt >> 3;
    const int h    = (nt & 7) * 16 + m16;
    const float* __restrict__ W = (z == 0) ? Wq : (z == 1) ? Wk : Wv;

    bf16x8_t v;
    #pragma unroll
    for (int e = 0; e < 8; ++e)
        v[e] = (__bf16)W[(t * 32 + quad * 8 + e) * H_ + h];
    *(bf16x8_t*)&WB[((long)pair * 64 + lane) * 8] = v;
}

// ---------------------------------------------------------------------------
// Fused projection, v8 = v7 + latency decoupling. v7 post-mortem: traffic
// floors fine (TA/L2 ~24us) but all pipes <=11% -> per-step critical path =
// same-step load latency (b waited by MFMA in-step; x drained by in-step
// barrier). Fix: (1) b-frag REGISTER double-buffer: b(t+1) loads overlap
// MFMAs on b(t) -> full step of latency cover. (2) x prefetch distance 2,
// 3 LDS buffers: barrier publishes x(t+1) issued at t-1. Explicit
// vmcnt(7) (= current step's issues) before s_barrier, never 0 in-loop.
// Loop fully unrolled -> all reg indices static. Block = 32 rows x 384
// cols (grid 1024: x read ONCE), 4 waves, wave = 2 a-frags x 6 b-frags =
// 12 MFMA/step. LDS 12 KB -> 4 blk/CU, 16 waves/CU.
// ---------------------------------------------------------------------------
__global__ __launch_bounds__(256, 4) void proj_kernel(
    const float*  __restrict__ x,
    const __bf16* __restrict__ WB,
    __bf16* __restrict__ qo,
    __bf16* __restrict__ ko,
    __bf16* __restrict__ vo)
{
    __shared__ float XS[3][32 * 32];     // fp32 x tiles, 4 KB each

    const int tid  = threadIdx.x;
    const int w    = tid >> 6;
    const int lane = tid & 63;
    const int m16  = lane & 15;
    const int quad = lane >> 4;

    const long r0 = (long)blockIdx.x * 32;

    // x staging lane map (pre-swizzled GLOBAL source, linear LDS dest)
    const int xl_row = lane >> 3;                  // 0..7 within wave's 8 rows
    const int xl_u   = (lane & 7) ^ xl_row;        // f32 4-elem unit

    // wave's b-frag base: n-tiles w*6..w*6+5
    const __bf16* __restrict__ wp = WB + (long)(w * 6) * 32 * 512 + lane * 8;

    f32x4_t acc[2][6];
    #pragma unroll
    for (int hh = 0; hh < 2; ++hh)
        #pragma unroll
        for (int j = 0; j < 6; ++j) acc[hh][j] = f32x4_t{0, 0, 0, 0};

#define XSTAGE(T, BUF)                                                       \
    gload_lds16(&x[(r0 + w * 8 + xl_row) * C_ + (T) * 32 + xl_u * 4],        \
                &XS[BUF][w * 8 * 32]);

    bf16x8_t bb[2][6];

    // ---- prologue: x(0),x(1) in flight; b(0) in regs; publish x(0) ----
    XSTAGE(0, 0);
    XSTAGE(1, 1);
    #pragma unroll
    for (int j = 0; j < 6; ++j)
        bb[0][j] = *(const bf16x8_t*)(wp + (long)j * 32 * 512);
    asm volatile("s_waitcnt vmcnt(7)" ::: "memory");   // retire x(0); keep x(1)+b(0)
    __builtin_amdgcn_sched_barrier(0);
    __builtin_amdgcn_s_barrier();
    __builtin_amdgcn_sched_barrier(0);

    const int asw = m16 & 7;                       // x unit swizzle (read side)

    #pragma unroll
    for (int t = 0; t < 32; ++t) {
        // issue next-next x and next b FIRST (their latency hides under MFMAs)
        if (t + 2 < 32) XSTAGE(t + 2, (t + 2) % 3);
        if (t + 1 < 32) {
            #pragma unroll
            for (int j = 0; j < 6; ++j)
                bb[(t + 1) & 1][j] =
                    *(const bf16x8_t*)(wp + ((long)j * 32 + (t + 1)) * 512);
        }

        // a-frags: fp32 -> bf16, swizzled LDS read (buffer t%3, static)
        bf16x8_t a[2];
        #pragma unroll
        for (int hh = 0; hh < 2; ++hh) {
            const int row = hh * 16 + m16;
            f32x4_t lo = *(const f32x4_t*)&XS[t % 3][row * 32 + (((quad * 2 + 0) ^ asw) << 2)];
            f32x4_t hi = *(const f32x4_t*)&XS[t % 3][row * 32 + (((quad * 2 + 1) ^ asw) << 2)];
            #pragma unroll
            for (int jj = 0; jj < 4; ++jj) {
                a[hh][jj]     = (__bf16)lo[jj];
                a[hh][4 + jj] = (__bf16)hi[jj];
            }
        }

        // 12 MFMAs on the PRE-LOADED b(t) set (compiler's wait here retires
        // b(t) [issued t-1] and transitively x(t+1) [older])
        #pragma unroll
        for (int j = 0; j < 6; ++j)
            #pragma unroll
            for (int hh = 0; hh < 2; ++hh)
                acc[hh][j] = MFMA_16x16x32_BF16(a[hh], bb[t & 1][j], acc[hh][j]);

        // publish XS[t+1] (already retired per above); keep t+1/t+2 loads in flight
        if (t < 31) {
            __builtin_amdgcn_sched_barrier(0);
            if (t + 2 < 32) asm volatile("s_waitcnt vmcnt(7)" ::: "memory");
            else            asm volatile("s_waitcnt vmcnt(6)" ::: "memory");
            __builtin_amdgcn_s_barrier();
            __builtin_amdgcn_sched_barrier(0);
        }
    }
#undef XSTAGE

    // Epilogue. C/D: col = m16 (n), row = quad*4 + r (m).
    #pragma unroll
    for (int hh = 0; hh < 2; ++hh) {
        const long rbase = r0 + hh * 16 + quad * 4;
        #pragma unroll
        for (int j = 0; j < 6; ++j) {
            const int nt = w * 6 + j;
            const int z  = nt >> 3;
            const int h  = (nt & 7) * 16 + m16;
            if (z < 2) {
                __bf16* __restrict__ o = z ? ko : qo;
                #pragma unroll
                for (int r = 0; r < 4; ++r)
                    o[(rbase + r) * H_ + h] = (__bf16)acc[hh][j][r];
            } else {
                long bb2 = rbase >> 11, tt = rbase & 2047;  // rows stay in batch
                bf16x4_t pk;
                #pragma unroll
                for (int r = 0; r < 4; ++r) pk[r] = (__bf16)acc[hh][j][r];
                *(bf16x4_t*)&vo[bb2 * (H_ * (long)T_) + h * (long)T_ + tt] = pk;
            }
        }
    }
}

// ---------------------------------------------------------------------------
// Flash attention, causal, transposed-score, LDS-SHARED K/V tiles.
// (unchanged from the 275 µs baseline)
// ---------------------------------------------------------------------------
__global__ __launch_bounds__(256) void attn_kernel(
    const __bf16* __restrict__ q,   // [B][T][H]
    const __bf16* __restrict__ k,   // [B][T][H]
    const __bf16* __restrict__ vT,  // [B][H][T]
    float* __restrict__ out)        // [B][T][H] fp32
{
    __shared__ __bf16 KS[64 * 136];     // [krow][h], pad 8  (17.4 KB)
    __shared__ __bf16 VS[128 * 72];     // [h][t],    pad 8  (18.4 KB)
    __shared__ __bf16 PS[4][16 * 72];   // per-wave P [q][k], pad 8 (9.2 KB)

    const int L   = blockIdx.x;
    const int b   = L & 15;
    const int Lh  = L >> 4;                       // 0..31
    const int qb  = (Lh < 16) ? (31 - Lh) : (Lh - 16);   // heavy first, CU-paired

    const int tid  = threadIdx.x;
    const int w    = tid >> 6;
    const int lane = tid & 63;
    const int m16  = lane & 15;
    const int quad = lane >> 4;
    const int koff = quad * 8;

    const __bf16* __restrict__ qp = q  + (long)b * T_ * H_;
    const __bf16* __restrict__ kp = k  + (long)b * T_ * H_;
    const __bf16* __restrict__ vp = vT + (long)b * H_ * T_;

    const int q0w = qb * 64 + w * 16;             // wave's q-tile base
    const int qg  = q0w + m16;                    // this lane's q row

    // Q^T B-fragments (lane n=m16=q, k=h)
    bf16x8_t qfr[4];
    #pragma unroll
    for (int s = 0; s < 4; ++s)
        qfr[s] = *(const bf16x8_t*)&qp[(q0w + m16) * H_ + s * 32 + koff];

    f32x4_t acc[8];                               // O^T: row=h, col=q
    #pragma unroll
    for (int i = 0; i < 8; ++i) acc[i] = f32x4_t{0, 0, 0, 0};
    float mrun = -1e30f, lrun = 0.f;

    __bf16* Pb = &PS[w][0];
    const float SC = 0.08838834764831845f;        // 1/sqrt(128)
    const int kend = qb * 64 + 64;

    // staging coords
    const int krow = tid >> 4, kc16 = tid & 15;   // K: 16 thr/row (256B)
    const int vrow = tid >> 3, vc8  = tid & 7;    // V: 8 thr/row (128B)

    for (int tk0 = 0; tk0 < kend; tk0 += 64) {
        __syncthreads();                          // prev compute done
        #pragma unroll
        for (int ch = 0; ch < 4; ++ch) {
            int r = krow + ch * 16;
            *(bf16x8_t*)&KS[r * 136 + kc16 * 8] =
                *(const bf16x8_t*)&kp[(tk0 + r) * H_ + kc16 * 8];
        }
        #pragma unroll
        for (int ch = 0; ch < 4; ++ch) {
            int hh = vrow + ch * 32;
            *(bf16x8_t*)&VS[hh * 72 + vc8 * 8] =
                *(const bf16x8_t*)&vp[hh * (long)T_ + tk0 + vc8 * 8];
        }
        __syncthreads();                          // tiles ready

        // ---- S^T = K Q^T : 4 S-tiles of 16 k-rows ----
        f32x4_t st[4];
        #pragma unroll
        for (int kt = 0; kt < 4; ++kt) {
            f32x4_t s = f32x4_t{0, 0, 0, 0};
            #pragma unroll
            for (int sI = 0; sI < 4; ++sI) {
                bf16x8_t kf = *(const bf16x8_t*)&KS[(kt * 16 + m16) * 136 + sI * 32 + koff];
                s = MFMA_16x16x32_BF16(kf, qfr[sI], s);
            }
            st[kt] = s;
        }

        // ---- scale (+ causal mask only on boundary tiles, wave-uniform) ----
        float vv[4][4];
        if (tk0 + 63 <= q0w) {                    // fully unmasked
            #pragma unroll
            for (int kt = 0; kt < 4; ++kt)
                #pragma unroll
                for (int r = 0; r < 4; ++r)
                    vv[kt][r] = st[kt][r] * SC;
        } else {
            #pragma unroll
            for (int kt = 0; kt < 4; ++kt)
                #pragma unroll
                for (int r = 0; r < 4; ++r) {
                    int kg = tk0 + kt * 16 + quad * 4 + r;
                    vv[kt][r] = (kg <= qg) ? st[kt][r] * SC : -1e30f;
                }
        }

        float mloc = -1e30f;
        #pragma unroll
        for (int kt = 0; kt < 4; ++kt)
            #pragma unroll
            for (int r = 0; r < 4; ++r)
                mloc = fmaxf(mloc, vv[kt][r]);
        mloc = fmaxf(mloc, __shfl_xor(mloc, 16, 64));
        mloc = fmaxf(mloc, __shfl_xor(mloc, 32, 64));

        float mnew = fmaxf(mrun, mloc);
        float al   = __expf(mrun - mnew);
        float psum = 0.f;
        #pragma unroll
        for (int kt = 0; kt < 4; ++kt) {
            bf16x4_t pk;
            #pragma unroll
            for (int r = 0; r < 4; ++r) {
                float p = __expf(vv[kt][r] - mnew);
                psum += p;
                pk[r] = (__bf16)p;
            }
            *(bf16x4_t*)&Pb[m16 * 72 + kt * 16 + quad * 4] = pk;
        }
        psum += __shfl_xor(psum, 16, 64);
        psum += __shfl_xor(psum, 32, 64);
        mrun = mnew;
        lrun = lrun * al + psum;

        #pragma unroll
        for (int i = 0; i < 8; ++i)
            #pragma unroll
            for (int r = 0; r < 4; ++r)
                acc[i][r] *= al;

        // ---- O^T += V^T P^T : two K=32 halves over the 64-wide tile ----
        #pragma unroll
        for (int half = 0; half < 2; ++half) {
            bf16x8_t pa = *(const bf16x8_t*)&Pb[m16 * 72 + half * 32 + koff];
            #pragma unroll
            for (int i = 0; i < 8; ++i) {
                bf16x8_t vf = *(const bf16x8_t*)&VS[(i * 16 + m16) * 72 + half * 32 + koff];
                acc[i] = MFMA_16x16x32_BF16(vf, pa, acc[i]);
            }
        }
    }

    // ---- epilogue: O[q][h] = acc/lrun, f32x4 stores ----
    float* __restrict__ ob = out + (long)b * T_ * H_;
    const float inv = 1.f / lrun;
    #pragma unroll
    for (int i = 0; i < 8; ++i) {
        f32x4_t o;
        #pragma unroll
        for (int r = 0; r < 4; ++r) o[r] = acc[i][r] * inv;
        *(f32x4_t*)&ob[(q0w + m16) * H_ + i * 16 + quad * 4] = o;
    }
}

// ---------------------------------------------------------------------------
extern "C" void kernel_launch(void* const* d_in, const int* in_sizes, int n_in,
                              void* d_out, int out_size, void* d_ws, size_t ws_size,
                              hipStream_t stream)
{
    // setup_inputs order: x, Wk, Wq, Wv — all float32
    const float* x  = (const float*)d_in[0];
    const float* Wk = (const float*)d_in[1];
    const float* Wq = (const float*)d_in[2];
    const float* Wv = (const float*)d_in[3];

    // ws: q [M,H] bf16 | k [M,H] bf16 | vT [B][H][T] bf16 | WB [24][32][64][8] bf16
    __bf16* qws = (__bf16*)d_ws;
    __bf16* kws = qws + M_ * H_;
    __bf16* vws = kws + M_ * H_;
    __bf16* WB  = vws + (long)B_ * H_ * T_;
    float*  out = (float*)d_out;

    wt_kernel  <<<dim3(192), 256, 0, stream>>>(Wq, Wk, Wv, WB);
    proj_kernel<<<dim3((int)(M_ / 32)), 256, 0, stream>>>(x, WB, qws, kws, vws);
    attn_kernel<<<dim3(512), 256, 0, stream>>>(qws, kws, vws, out);
}

// Round 10
// 273.535 us; speedup vs baseline: 1.0611x; 1.0611x over previous
//
#include <hip/hip_runtime.h>
#include <hip/hip_bf16.h>

typedef __bf16 bf16x8_t __attribute__((ext_vector_type(8)));
typedef __bf16 bf16x4_t __attribute__((ext_vector_type(4)));
typedef float  f32x4_t  __attribute__((ext_vector_type(4)));

#define MFMA_16x16x32_BF16(A, B, C) __builtin_amdgcn_mfma_f32_16x16x32_bf16((A), (B), (C), 0, 0, 0)

static constexpr int B_ = 16;
static constexpr int T_ = 2048;
static constexpr int C_ = 1024;
static constexpr int H_ = 128;
static constexpr long M_ = (long)B_ * T_;   // 32768 rows

__device__ __forceinline__ void gload_lds16(const void* g, void* l)
{
    __builtin_amdgcn_global_load_lds(
        (const __attribute__((address_space(1))) void*)g,
        (__attribute__((address_space(3))) void*)l, 16, 0, 0);
}

// ---------------------------------------------------------------------------
// W transpose: WT[z][h][c] = bf16(W_z[c][h]).  Flat: WT[n][c], n = z*128+h.
// ---------------------------------------------------------------------------
__global__ __launch_bounds__(128) void wt_kernel(
    const float* __restrict__ Wq, const float* __restrict__ Wk,
    const float* __restrict__ Wv, __bf16* __restrict__ WT)
{
    const int z = blockIdx.y;
    const float* __restrict__ W = (z == 0) ? Wq : (z == 1) ? Wk : Wv;
    const int h  = threadIdx.x;
    const int c0 = blockIdx.x * 8;
    bf16x8_t v;
    #pragma unroll
    for (int j = 0; j < 8; ++j)
        v[j] = (__bf16)W[(c0 + j) * H_ + h];
    *(bf16x8_t*)&WT[((long)z * H_ + h) * C_ + c0] = v;
}

// ---------------------------------------------------------------------------
// Fused projection, v5 build (round-5 verified, 78 us — session best).
// 128x384 block, grid 256, 8 waves (2m x 4n), wave = 64r x 96c = 4a x 6b
// = 24 MFMA/k-step. 3 LDS buffers, prefetch distance 2, per-step vmcnt(5)
// before the barrier (loads never drained to 0 in-loop). All staging via
// global_load_lds (x as fp32, cvt at frag build). Swizzles both-sides:
// x unit^=row&7, W unit^=(row>>1)&3. LDS 120 KB.
// ---------------------------------------------------------------------------
__global__ __launch_bounds__(512, 2) void proj_kernel(
    const float*  __restrict__ x,
    const __bf16* __restrict__ WT,
    __bf16* __restrict__ qo,
    __bf16* __restrict__ ko,
    __bf16* __restrict__ vo)
{
    __shared__ float  XS[3][128 * 32];   // fp32 x tiles, 16 KB each
    __shared__ __bf16 WS[3][384 * 32];   // bf16 W tiles, 24 KB each

    const int tid  = threadIdx.x;
    const int w    = tid >> 6;
    const int lane = tid & 63;
    const int m16  = lane & 15;
    const int quad = lane >> 4;
    const int wm   = w >> 2;             // row-half 0..1 (64 rows)
    const int wn   = w & 3;              // col-quarter 0..3 (6 n-tiles)

    const long r0 = (long)blockIdx.x * 128;

    // staging lane maps (pre-swizzled GLOBAL source, linear LDS dest)
    const int xl_row = lane >> 3;                     // row within 8-row chunk
    const int xl_u   = (lane & 7) ^ xl_row;           // f32 unit (4 floats)
    const int wl_row = lane >> 2;                     // row within 16-row chunk
    const int wl_u   = (lane & 3) ^ ((lane >> 3) & 3);// bf16 unit (8 elems)

    f32x4_t acc[4][6];
    #pragma unroll
    for (int hh = 0; hh < 4; ++hh)
        #pragma unroll
        for (int j = 0; j < 6; ++j) acc[hh][j] = f32x4_t{0, 0, 0, 0};

#define ISSUE(T, BUF)                                                        \
    {                                                                        \
        const int k0_ = (T) * 32;                                            \
        _Pragma("unroll")                                                    \
        for (int ch = 0; ch < 2; ++ch) {                                     \
            const int rb = w * 8 + ch * 64;                                  \
            gload_lds16(&x[(r0 + rb + xl_row) * C_ + k0_ + xl_u * 4],        \
                        &XS[BUF][rb * 32]);                                  \
        }                                                                    \
        _Pragma("unroll")                                                    \
        for (int ch = 0; ch < 3; ++ch) {                                     \
            const int rb = w * 48 + ch * 16;                                 \
            gload_lds16(&WT[(long)(rb + wl_row) * C_ + k0_ + wl_u * 8],      \
                        &WS[BUF][rb * 32]);                                  \
        }                                                                    \
    }

    // ---- prologue: buffers 0 and 1 in flight; wait only for buffer 0 ----
    ISSUE(0, 0);
    ISSUE(1, 1);
    asm volatile("s_waitcnt vmcnt(5)" ::: "memory");
    __builtin_amdgcn_sched_barrier(0);
    __builtin_amdgcn_s_barrier();
    __builtin_amdgcn_sched_barrier(0);

    const int asw = m16 & 7;                           // x unit swizzle
    const int qsw = (quad ^ ((m16 >> 1) & 3)) << 3;    // W bf16-elem offset

    for (int t = 0; t < 32; ++t) {
        const int cur = t % 3;
        if (t + 2 < 32) ISSUE(t + 2, (t + 2) % 3);
        __builtin_amdgcn_sched_barrier(0);

        // a-frags: fp32 -> bf16, swizzled read
        bf16x8_t a[4];
        #pragma unroll
        for (int hh = 0; hh < 4; ++hh) {
            const int row = wm * 64 + hh * 16 + m16;
            f32x4_t lo = *(const f32x4_t*)&XS[cur][row * 32 + (((quad * 2 + 0) ^ asw) << 2)];
            f32x4_t hi = *(const f32x4_t*)&XS[cur][row * 32 + (((quad * 2 + 1) ^ asw) << 2)];
            #pragma unroll
            for (int jj = 0; jj < 4; ++jj) {
                a[hh][jj]     = (__bf16)lo[jj];
                a[hh][4 + jj] = (__bf16)hi[jj];
            }
        }
        // b-frags + 24 MFMAs (b reused x4)
        #pragma unroll
        for (int j = 0; j < 6; ++j) {
            const int row = wn * 96 + j * 16 + m16;
            bf16x8_t b = *(const bf16x8_t*)&WS[cur][row * 32 + qsw];
            #pragma unroll
            for (int hh = 0; hh < 4; ++hh)
                acc[hh][j] = MFMA_16x16x32_BF16(a[hh], b, acc[hh][j]);
        }

        __builtin_amdgcn_sched_barrier(0);
        if (t + 2 < 32) asm volatile("s_waitcnt vmcnt(5)" ::: "memory");
        else            asm volatile("s_waitcnt vmcnt(0)" ::: "memory");
        asm volatile("s_waitcnt lgkmcnt(0)" ::: "memory");
        __builtin_amdgcn_s_barrier();          // publish buf[t+1]; reads done
        __builtin_amdgcn_sched_barrier(0);
    }
#undef ISSUE

    // Epilogue. C/D: col = m16 (n), row = quad*4 + r (m).
    #pragma unroll
    for (int hh = 0; hh < 4; ++hh) {
        const long rbase = r0 + wm * 64 + hh * 16 + quad * 4;
        #pragma unroll
        for (int j = 0; j < 6; ++j) {
            const int nt = wn * 6 + j;
            const int z  = nt >> 3;
            const int h  = (nt & 7) * 16 + m16;
            if (z < 2) {
                __bf16* __restrict__ o = z ? ko : qo;
                #pragma unroll
                for (int r = 0; r < 4; ++r)
                    o[(rbase + r) * H_ + h] = (__bf16)acc[hh][j][r];
            } else {
                long bb = rbase >> 11, tt = rbase & 2047;  // rows stay in batch
                bf16x4_t pk;
                #pragma unroll
                for (int r = 0; r < 4; ++r) pk[r] = (__bf16)acc[hh][j][r];
                *(bf16x4_t*)&vo[bb * (H_ * (long)T_) + h * (long)T_ + tt] = pk;
            }
        }
    }
}

// ---------------------------------------------------------------------------
// Flash attention, SPLIT-K (split=2). Baseline attn had grid 512 = 2
// blocks/CU, 8 waves/CU, barrier-locked staging — same latency disease as
// proj. Split the causal k-sweep across 2 blocks: grid 1024 (b, qb, half),
// half0 sweeps tiles [0, n0), half1 [n0, ntile), ntile = qb+1,
// n0 = ceil(ntile/2). Each writes UNNORMALIZED O^T acc + per-row (m, l);
// merge_kernel combines. Empty half (qb=0, half1) writes m=-1e30, l=0 ->
// merge weight exp(-1e30-m)=0. Occupancy: LDS 45 KB -> 3 blocks/CU.
// Compute body identical to the verified baseline.
// ---------------------------------------------------------------------------
__global__ __launch_bounds__(256) void attn_kernel(
    const __bf16* __restrict__ q,   // [B][T][H]
    const __bf16* __restrict__ k,   // [B][T][H]
    const __bf16* __restrict__ vT,  // [B][H][T]
    float* __restrict__ Opart,      // [2][B][T][H] fp32, unnormalized
    float* __restrict__ mpart,      // [2][B*T]
    float* __restrict__ lpart)      // [2][B*T]
{
    __shared__ __bf16 KS[64 * 136];     // [krow][h], pad 8  (17.4 KB)
    __shared__ __bf16 VS[128 * 72];     // [h][t],    pad 8  (18.4 KB)
    __shared__ __bf16 PS[4][16 * 72];   // per-wave P [q][k], pad 8 (9.2 KB)

    const int bid  = blockIdx.x;
    const int half = bid & 1;
    const int L    = bid >> 1;
    const int b    = L & 15;
    const int Lh   = L >> 4;                      // 0..31
    const int qb   = (Lh < 16) ? (31 - Lh) : (Lh - 16);  // heavy first

    const int tid  = threadIdx.x;
    const int w    = tid >> 6;
    const int lane = tid & 63;
    const int m16  = lane & 15;
    const int quad = lane >> 4;
    const int koff = quad * 8;

    const __bf16* __restrict__ qp = q  + (long)b * T_ * H_;
    const __bf16* __restrict__ kp = k  + (long)b * T_ * H_;
    const __bf16* __restrict__ vp = vT + (long)b * H_ * T_;

    const int q0w = qb * 64 + w * 16;             // wave's q-tile base
    const int qg  = q0w + m16;                    // this lane's q row

    // Q^T B-fragments (lane n=m16=q, k=h)
    bf16x8_t qfr[4];
    #pragma unroll
    for (int s = 0; s < 4; ++s)
        qfr[s] = *(const bf16x8_t*)&qp[(q0w + m16) * H_ + s * 32 + koff];

    f32x4_t acc[8];                               // O^T: row=h, col=q
    #pragma unroll
    for (int i = 0; i < 8; ++i) acc[i] = f32x4_t{0, 0, 0, 0};
    float mrun = -1e30f, lrun = 0.f;

    __bf16* Pb = &PS[w][0];
    const float SC = 0.08838834764831845f;        // 1/sqrt(128)

    // tile range for this half
    const int ntile = qb + 1;
    const int n0    = (ntile + 1) >> 1;
    const int tt0   = half ? n0 : 0;
    const int tt1   = half ? ntile : n0;

    // staging coords
    const int krow = tid >> 4, kc16 = tid & 15;   // K: 16 thr/row (256B)
    const int vrow = tid >> 3, vc8  = tid & 7;    // V: 8 thr/row (128B)

    for (int tt = tt0; tt < tt1; ++tt) {
        const int tk0 = tt * 64;
        __syncthreads();                          // prev compute done
        #pragma unroll
        for (int ch = 0; ch < 4; ++ch) {
            int r = krow + ch * 16;
            *(bf16x8_t*)&KS[r * 136 + kc16 * 8] =
                *(const bf16x8_t*)&kp[(tk0 + r) * H_ + kc16 * 8];
        }
        #pragma unroll
        for (int ch = 0; ch < 4; ++ch) {
            int hh = vrow + ch * 32;
            *(bf16x8_t*)&VS[hh * 72 + vc8 * 8] =
                *(const bf16x8_t*)&vp[hh * (long)T_ + tk0 + vc8 * 8];
        }
        __syncthreads();                          // tiles ready

        // ---- S^T = K Q^T : 4 S-tiles of 16 k-rows ----
        f32x4_t st[4];
        #pragma unroll
        for (int kt = 0; kt < 4; ++kt) {
            f32x4_t s = f32x4_t{0, 0, 0, 0};
            #pragma unroll
            for (int sI = 0; sI < 4; ++sI) {
                bf16x8_t kf = *(const bf16x8_t*)&KS[(kt * 16 + m16) * 136 + sI * 32 + koff];
                s = MFMA_16x16x32_BF16(kf, qfr[sI], s);
            }
            st[kt] = s;
        }

        // ---- scale (+ causal mask only on boundary tiles, wave-uniform) ----
        float vv[4][4];
        if (tk0 + 63 <= q0w) {                    // fully unmasked
            #pragma unroll
            for (int kt = 0; kt < 4; ++kt)
                #pragma unroll
                for (int r = 0; r < 4; ++r)
                    vv[kt][r] = st[kt][r] * SC;
        } else {
            #pragma unroll
            for (int kt = 0; kt < 4; ++kt)
                #pragma unroll
                for (int r = 0; r < 4; ++r) {
                    int kg = tk0 + kt * 16 + quad * 4 + r;
                    vv[kt][r] = (kg <= qg) ? st[kt][r] * SC : -1e30f;
                }
        }

        float mloc = -1e30f;
        #pragma unroll
        for (int kt = 0; kt < 4; ++kt)
            #pragma unroll
            for (int r = 0; r < 4; ++r)
                mloc = fmaxf(mloc, vv[kt][r]);
        mloc = fmaxf(mloc, __shfl_xor(mloc, 16, 64));
        mloc = fmaxf(mloc, __shfl_xor(mloc, 32, 64));

        float mnew = fmaxf(mrun, mloc);
        float al   = __expf(mrun - mnew);
        float psum = 0.f;
        #pragma unroll
        for (int kt = 0; kt < 4; ++kt) {
            bf16x4_t pk;
            #pragma unroll
            for (int r = 0; r < 4; ++r) {
                float p = __expf(vv[kt][r] - mnew);
                psum += p;
                pk[r] = (__bf16)p;
            }
            *(bf16x4_t*)&Pb[m16 * 72 + kt * 16 + quad * 4] = pk;
        }
        psum += __shfl_xor(psum, 16, 64);
        psum += __shfl_xor(psum, 32, 64);
        mrun = mnew;
        lrun = lrun * al + psum;

        #pragma unroll
        for (int i = 0; i < 8; ++i)
            #pragma unroll
            for (int r = 0; r < 4; ++r)
                acc[i][r] *= al;

        // ---- O^T += V^T P^T : two K=32 halves over the 64-wide tile ----
        #pragma unroll
        for (int hf = 0; hf < 2; ++hf) {
            bf16x8_t pa = *(const bf16x8_t*)&Pb[m16 * 72 + hf * 32 + koff];
            #pragma unroll
            for (int i = 0; i < 8; ++i) {
                bf16x8_t vf = *(const bf16x8_t*)&VS[(i * 16 + m16) * 72 + hf * 32 + koff];
                acc[i] = MFMA_16x16x32_BF16(vf, pa, acc[i]);
            }
        }
    }

    // ---- epilogue: UNNORMALIZED O + per-row (m, l) ----
    float* __restrict__ ob = Opart + ((long)half * B_ + b) * T_ * H_;
    #pragma unroll
    for (int i = 0; i < 8; ++i)
        *(f32x4_t*)&ob[(q0w + m16) * H_ + i * 16 + quad * 4] = acc[i];
    if (quad == 0) {
        const long rix = (long)half * M_ + (long)b * T_ + q0w + m16;
        mpart[rix] = mrun;
        lpart[rix] = lrun;
    }
}

// ---------------------------------------------------------------------------
// Merge the 2 split-K partials: out = sum_i exp(mi-m) Oi / sum_i exp(mi-m) li
// ---------------------------------------------------------------------------
__global__ __launch_bounds__(256) void merge_kernel(
    const float* __restrict__ Opart, const float* __restrict__ mpart,
    const float* __restrict__ lpart, float* __restrict__ out)
{
    const long idx = (long)blockIdx.x * 256 + threadIdx.x;   // f32x4 index
    const long row = idx >> 5;                               // global q-row
    const float m0 = mpart[row], m1 = mpart[M_ + row];
    const float l0 = lpart[row], l1 = lpart[M_ + row];
    const float m  = fmaxf(m0, m1);
    const float a0 = __expf(m0 - m), a1 = __expf(m1 - m);
    const float inv = 1.f / (a0 * l0 + a1 * l1);
    f32x4_t o0 = *(const f32x4_t*)&Opart[idx * 4];
    f32x4_t o1 = *(const f32x4_t*)&Opart[(long)M_ * H_ + idx * 4];
    f32x4_t o;
    #pragma unroll
    for (int r = 0; r < 4; ++r) o[r] = (a0 * o0[r] + a1 * o1[r]) * inv;
    *(f32x4_t*)&out[idx * 4] = o;
}

// ---------------------------------------------------------------------------
extern "C" void kernel_launch(void* const* d_in, const int* in_sizes, int n_in,
                              void* d_out, int out_size, void* d_ws, size_t ws_size,
                              hipStream_t stream)
{
    // setup_inputs order: x, Wk, Wq, Wv — all float32
    const float* x  = (const float*)d_in[0];
    const float* Wk = (const float*)d_in[1];
    const float* Wq = (const float*)d_in[2];
    const float* Wv = (const float*)d_in[3];

    // ws: q | k | vT [B][H][T] | WT [3][H][C]  (all bf16)
    //     | Opart [2][B][T][H] f32 | mpart [2][B*T] f32 | lpart [2][B*T] f32
    __bf16* qws = (__bf16*)d_ws;
    __bf16* kws = qws + M_ * H_;
    __bf16* vws = kws + M_ * H_;
    __bf16* WT  = vws + (long)B_ * H_ * T_;
    float*  Opart = (float*)(WT + 3L * H_ * C_);
    float*  mpart = Opart + 2L * M_ * H_;
    float*  lpart = mpart + 2L * M_;
    float*  out = (float*)d_out;

    wt_kernel   <<<dim3(C_ / 8, 3), 128, 0, stream>>>(Wq, Wk, Wv, WT);
    proj_kernel <<<dim3((int)(M_ / 128)), 512, 0, stream>>>(x, WT, qws, kws, vws);
    attn_kernel <<<dim3(1024), 256, 0, stream>>>(qws, kws, vws, Opart, mpart, lpart);
    merge_kernel<<<dim3((int)(M_ * H_ / 4 / 256)), 256, 0, stream>>>(Opart, mpart, lpart, out);
}

// Round 12
// 272.686 us; speedup vs baseline: 1.0644x; 1.0031x over previous
//
#include <hip/hip_runtime.h>
#include <hip/hip_bf16.h>

typedef __bf16 bf16x8_t __attribute__((ext_vector_type(8)));
typedef __bf16 bf16x4_t __attribute__((ext_vector_type(4)));
typedef float  f32x4_t  __attribute__((ext_vector_type(4)));

#define MFMA_16x16x32_BF16(A, B, C) __builtin_amdgcn_mfma_f32_16x16x32_bf16((A), (B), (C), 0, 0, 0)

static constexpr int B_ = 16;
static constexpr int T_ = 2048;
static constexpr int C_ = 1024;
static constexpr int H_ = 128;
static constexpr long M_ = (long)B_ * T_;   // 32768 rows

__device__ __forceinline__ void gload_lds16(const void* g, void* l)
{
    __builtin_amdgcn_global_load_lds(
        (const __attribute__((address_space(1))) void*)g,
        (__attribute__((address_space(3))) void*)l, 16, 0, 0);
}

// ---------------------------------------------------------------------------
// W transpose: WT[z][h][c] = bf16(W_z[c][h]).  Flat: WT[n][c], n = z*128+h.
// ---------------------------------------------------------------------------
__global__ __launch_bounds__(128) void wt_kernel(
    const float* __restrict__ Wq, const float* __restrict__ Wk,
    const float* __restrict__ Wv, __bf16* __restrict__ WT)
{
    const int z = blockIdx.y;
    const float* __restrict__ W = (z == 0) ? Wq : (z == 1) ? Wk : Wv;
    const int h  = threadIdx.x;
    const int c0 = blockIdx.x * 8;
    bf16x8_t v;
    #pragma unroll
    for (int j = 0; j < 8; ++j)
        v[j] = (__bf16)W[(c0 + j) * H_ + h];
    *(bf16x8_t*)&WT[((long)z * H_ + h) * C_ + c0] = v;
}

// ---------------------------------------------------------------------------
// Fused projection, v5 build (session-best proj, ~78-83 us).
// 128x384 block, grid 256, 8 waves (2m x 4n), wave = 64r x 96c = 4a x 6b
// = 24 MFMA/k-step. 3 LDS buffers, prefetch distance 2, per-step vmcnt(5)
// before the barrier. All staging via global_load_lds (x as fp32, cvt at
// frag build). Swizzles both-sides: x unit^=row&7, W unit^=(row>>1)&3.
// ---------------------------------------------------------------------------
__global__ __launch_bounds__(512, 2) void proj_kernel(
    const float*  __restrict__ x,
    const __bf16* __restrict__ WT,
    __bf16* __restrict__ qo,
    __bf16* __restrict__ ko,
    __bf16* __restrict__ vo)
{
    __shared__ float  XS[3][128 * 32];   // fp32 x tiles, 16 KB each
    __shared__ __bf16 WS[3][384 * 32];   // bf16 W tiles, 24 KB each

    const int tid  = threadIdx.x;
    const int w    = tid >> 6;
    const int lane = tid & 63;
    const int m16  = lane & 15;
    const int quad = lane >> 4;
    const int wm   = w >> 2;             // row-half 0..1 (64 rows)
    const int wn   = w & 3;              // col-quarter 0..3 (6 n-tiles)

    const long r0 = (long)blockIdx.x * 128;

    // staging lane maps (pre-swizzled GLOBAL source, linear LDS dest)
    const int xl_row = lane >> 3;                     // row within 8-row chunk
    const int xl_u   = (lane & 7) ^ xl_row;           // f32 unit (4 floats)
    const int wl_row = lane >> 2;                     // row within 16-row chunk
    const int wl_u   = (lane & 3) ^ ((lane >> 3) & 3);// bf16 unit (8 elems)

    f32x4_t acc[4][6];
    #pragma unroll
    for (int hh = 0; hh < 4; ++hh)
        #pragma unroll
        for (int j = 0; j < 6; ++j) acc[hh][j] = f32x4_t{0, 0, 0, 0};

#define ISSUE(T, BUF)                                                        \
    {                                                                        \
        const int k0_ = (T) * 32;                                            \
        _Pragma("unroll")                                                    \
        for (int ch = 0; ch < 2; ++ch) {                                     \
            const int rb = w * 8 + ch * 64;                                  \
            gload_lds16(&x[(r0 + rb + xl_row) * C_ + k0_ + xl_u * 4],        \
                        &XS[BUF][rb * 32]);                                  \
        }                                                                    \
        _Pragma("unroll")                                                    \
        for (int ch = 0; ch < 3; ++ch) {                                     \
            const int rb = w * 48 + ch * 16;                                 \
            gload_lds16(&WT[(long)(rb + wl_row) * C_ + k0_ + wl_u * 8],      \
                        &WS[BUF][rb * 32]);                                  \
        }                                                                    \
    }

    // ---- prologue: buffers 0 and 1 in flight; wait only for buffer 0 ----
    ISSUE(0, 0);
    ISSUE(1, 1);
    asm volatile("s_waitcnt vmcnt(5)" ::: "memory");
    __builtin_amdgcn_sched_barrier(0);
    __builtin_amdgcn_s_barrier();
    __builtin_amdgcn_sched_barrier(0);

    const int asw = m16 & 7;                           // x unit swizzle
    const int qsw = (quad ^ ((m16 >> 1) & 3)) << 3;    // W bf16-elem offset

    for (int t = 0; t < 32; ++t) {
        const int cur = t % 3;
        if (t + 2 < 32) ISSUE(t + 2, (t + 2) % 3);
        __builtin_amdgcn_sched_barrier(0);

        // a-frags: fp32 -> bf16, swizzled read
        bf16x8_t a[4];
        #pragma unroll
        for (int hh = 0; hh < 4; ++hh) {
            const int row = wm * 64 + hh * 16 + m16;
            f32x4_t lo = *(const f32x4_t*)&XS[cur][row * 32 + (((quad * 2 + 0) ^ asw) << 2)];
            f32x4_t hi = *(const f32x4_t*)&XS[cur][row * 32 + (((quad * 2 + 1) ^ asw) << 2)];
            #pragma unroll
            for (int jj = 0; jj < 4; ++jj) {
                a[hh][jj]     = (__bf16)lo[jj];
                a[hh][4 + jj] = (__bf16)hi[jj];
            }
        }
        // b-frags + 24 MFMAs (b reused x4)
        #pragma unroll
        for (int j = 0; j < 6; ++j) {
            const int row = wn * 96 + j * 16 + m16;
            bf16x8_t b = *(const bf16x8_t*)&WS[cur][row * 32 + qsw];
            #pragma unroll
            for (int hh = 0; hh < 4; ++hh)
                acc[hh][j] = MFMA_16x16x32_BF16(a[hh], b, acc[hh][j]);
        }

        __builtin_amdgcn_sched_barrier(0);
        if (t + 2 < 32) asm volatile("s_waitcnt vmcnt(5)" ::: "memory");
        else            asm volatile("s_waitcnt vmcnt(0)" ::: "memory");
        asm volatile("s_waitcnt lgkmcnt(0)" ::: "memory");
        __builtin_amdgcn_s_barrier();          // publish buf[t+1]; reads done
        __builtin_amdgcn_sched_barrier(0);
    }
#undef ISSUE

    // Epilogue. C/D: col = m16 (n), row = quad*4 + r (m).
    #pragma unroll
    for (int hh = 0; hh < 4; ++hh) {
        const long rbase = r0 + wm * 64 + hh * 16 + quad * 4;
        #pragma unroll
        for (int j = 0; j < 6; ++j) {
            const int nt = wn * 6 + j;
            const int z  = nt >> 3;
            const int h  = (nt & 7) * 16 + m16;
            if (z < 2) {
                __bf16* __restrict__ o = z ? ko : qo;
                #pragma unroll
                for (int r = 0; r < 4; ++r)
                    o[(rbase + r) * H_ + h] = (__bf16)acc[hh][j][r];
            } else {
                long bb = rbase >> 11, tt = rbase & 2047;  // rows stay in batch
                bf16x4_t pk;
                #pragma unroll
                for (int r = 0; r < 4; ++r) pk[r] = (__bf16)acc[hh][j][r];
                *(bf16x4_t*)&vo[bb * (H_ * (long)T_) + h * (long)T_ + tt] = pk;
            }
        }
    }
}

// ---------------------------------------------------------------------------
// Flash attention, split-K=2, QBLK=128 (8 waves, 512 thr). Staging (32 KB
// K/V per tile, 2 barriers) per 64 q-rows was the cost; QBLK=128 halves
// tiles/chip (8700 -> 4350). Grid 512 = EXACTLY 2 blocks/CU (LDS 54 KB),
// all co-resident; complementary qb decode pairs heavy+light halves per CU
// -> every CU sweeps exactly 17 tiles. Wave body identical to verified
// baseline (wave owns 16 q-rows). Fully-masked tiles are SELF-CORRECTING:
// while mrun=-1e30, p=1 garbage accumulates finitely; first real tile sets
// al=exp(-1e30-real)=0 which wipes acc; all-masked waves write m=-1e30 ->
// merge weight 0 x finite O = 0. ntile=2qb+2, n0=qb+1: both halves
// non-empty for all qb.
// ---------------------------------------------------------------------------
__global__ __launch_bounds__(512, 2) void attn_kernel(
    const __bf16* __restrict__ q,   // [B][T][H]
    const __bf16* __restrict__ k,   // [B][T][H]
    const __bf16* __restrict__ vT,  // [B][H][T]
    float* __restrict__ Opart,      // [2][B][T][H] fp32, unnormalized
    float* __restrict__ mpart,      // [2][B*T]
    float* __restrict__ lpart)      // [2][B*T]
{
    __shared__ __bf16 KS[64 * 136];     // [krow][h], pad 8  (17.4 KB)
    __shared__ __bf16 VS[128 * 72];     // [h][t],    pad 8  (18.4 KB)
    __shared__ __bf16 PS[8][16 * 72];   // per-wave P [q][k], pad 8 (18.4 KB)

    const int bid  = blockIdx.x;
    const int half = bid & 1;
    const int L    = bid >> 1;                    // 0..255
    const int b    = L & 15;
    const int Lh   = L >> 4;                      // 0..15
    const int qb   = (Lh < 8) ? (15 - Lh) : (Lh - 8);  // heavy first, CU-complementary

    const int tid  = threadIdx.x;
    const int w    = tid >> 6;                    // 0..7
    const int lane = tid & 63;
    const int m16  = lane & 15;
    const int quad = lane >> 4;
    const int koff = quad * 8;

    const __bf16* __restrict__ qp = q  + (long)b * T_ * H_;
    const __bf16* __restrict__ kp = k  + (long)b * T_ * H_;
    const __bf16* __restrict__ vp = vT + (long)b * H_ * T_;

    const int q0w = qb * 128 + w * 16;            // wave's q-tile base
    const int qg  = q0w + m16;                    // this lane's q row

    // Q^T B-fragments (lane n=m16=q, k=h)
    bf16x8_t qfr[4];
    #pragma unroll
    for (int s = 0; s < 4; ++s)
        qfr[s] = *(const bf16x8_t*)&qp[(q0w + m16) * H_ + s * 32 + koff];

    f32x4_t acc[8];                               // O^T: row=h, col=q
    #pragma unroll
    for (int i = 0; i < 8; ++i) acc[i] = f32x4_t{0, 0, 0, 0};
    float mrun = -1e30f, lrun = 0.f;

    __bf16* Pb = &PS[w][0];
    const float SC = 0.08838834764831845f;        // 1/sqrt(128)

    // tile range for this half (64-wide tiles)
    const int ntile = 2 * qb + 2;
    const int n0    = qb + 1;
    const int tt0   = half ? n0 : 0;
    const int tt1   = half ? ntile : n0;

    // staging coords (512 threads)
    const int krow = tid >> 4, kc16 = tid & 15;   // K: 16 thr/row, 32 rows/chunk
    const int vrow = tid >> 3, vc8  = tid & 7;    // V: 8 thr/row, 64 rows/chunk

    for (int tt = tt0; tt < tt1; ++tt) {
        const int tk0 = tt * 64;
        __syncthreads();                          // prev compute done
        #pragma unroll
        for (int ch = 0; ch < 2; ++ch) {
            int r = krow + ch * 32;
            *(bf16x8_t*)&KS[r * 136 + kc16 * 8] =
                *(const bf16x8_t*)&kp[(tk0 + r) * H_ + kc16 * 8];
        }
        #pragma unroll
        for (int ch = 0; ch < 2; ++ch) {
            int hh = vrow + ch * 64;
            *(bf16x8_t*)&VS[hh * 72 + vc8 * 8] =
                *(const bf16x8_t*)&vp[hh * (long)T_ + tk0 + vc8 * 8];
        }
        __syncthreads();                          // tiles ready

        // ---- S^T = K Q^T : 4 S-tiles of 16 k-rows ----
        f32x4_t st[4];
        #pragma unroll
        for (int kt = 0; kt < 4; ++kt) {
            f32x4_t s = f32x4_t{0, 0, 0, 0};
            #pragma unroll
            for (int sI = 0; sI < 4; ++sI) {
                bf16x8_t kf = *(const bf16x8_t*)&KS[(kt * 16 + m16) * 136 + sI * 32 + koff];
                s = MFMA_16x16x32_BF16(kf, qfr[sI], s);
            }
            st[kt] = s;
        }

        // ---- scale (+ causal mask only on boundary tiles, wave-uniform) ----
        float vv[4][4];
        if (tk0 + 63 <= q0w) {                    // fully unmasked
            #pragma unroll
            for (int kt = 0; kt < 4; ++kt)
                #pragma unroll
                for (int r = 0; r < 4; ++r)
                    vv[kt][r] = st[kt][r] * SC;
        } else {
            #pragma unroll
            for (int kt = 0; kt < 4; ++kt)
                #pragma unroll
                for (int r = 0; r < 4; ++r) {
                    int kg = tk0 + kt * 16 + quad * 4 + r;
                    vv[kt][r] = (kg <= qg) ? st[kt][r] * SC : -1e30f;
                }
        }

        float mloc = -1e30f;
        #pragma unroll
        for (int kt = 0; kt < 4; ++kt)
            #pragma unroll
            for (int r = 0; r < 4; ++r)
                mloc = fmaxf(mloc, vv[kt][r]);
        mloc = fmaxf(mloc, __shfl_xor(mloc, 16, 64));
        mloc = fmaxf(mloc, __shfl_xor(mloc, 32, 64));

        float mnew = fmaxf(mrun, mloc);
        float al   = __expf(mrun - mnew);
        float psum = 0.f;
        #pragma unroll
        for (int kt = 0; kt < 4; ++kt) {
            bf16x4_t pk;
            #pragma unroll
            for (int r = 0; r < 4; ++r) {
                float p = __expf(vv[kt][r] - mnew);
                psum += p;
                pk[r] = (__bf16)p;
            }
            *(bf16x4_t*)&Pb[m16 * 72 + kt * 16 + quad * 4] = pk;
        }
        psum += __shfl_xor(psum, 16, 64);
        psum += __shfl_xor(psum, 32, 64);
        mrun = mnew;
        lrun = lrun * al + psum;

        #pragma unroll
        for (int i = 0; i < 8; ++i)
            #pragma unroll
            for (int r = 0; r < 4; ++r)
                acc[i][r] *= al;

        // ---- O^T += V^T P^T : two K=32 halves over the 64-wide tile ----
        #pragma unroll
        for (int hf = 0; hf < 2; ++hf) {
            bf16x8_t pa = *(const bf16x8_t*)&Pb[m16 * 72 + hf * 32 + koff];
            #pragma unroll
            for (int i = 0; i < 8; ++i) {
                bf16x8_t vf = *(const bf16x8_t*)&VS[(i * 16 + m16) * 72 + hf * 32 + koff];
                acc[i] = MFMA_16x16x32_BF16(vf, pa, acc[i]);
            }
        }
    }

    // ---- epilogue: UNNORMALIZED O + per-row (m, l) ----
    float* __restrict__ ob = Opart + ((long)half * B_ + b) * T_ * H_;
    #pragma unroll
    for (int i = 0; i < 8; ++i)
        *(f32x4_t*)&ob[(q0w + m16) * H_ + i * 16 + quad * 4] = acc[i];
    if (quad == 0) {
        const long rix = (long)half * M_ + (long)b * T_ + q0w + m16;
        mpart[rix] = mrun;
        lpart[rix] = lrun;
    }
}

// ---------------------------------------------------------------------------
// Merge the 2 split-K partials: out = sum_i exp(mi-m) Oi / sum_i exp(mi-m) li
// ---------------------------------------------------------------------------
__global__ __launch_bounds__(256) void merge_kernel(
    const float* __restrict__ Opart, const float* __restrict__ mpart,
    const float* __restrict__ lpart, float* __restrict__ out)
{
    const long idx = (long)blockIdx.x * 256 + threadIdx.x;   // f32x4 index
    const long row = idx >> 5;                               // global q-row
    const float m0 = mpart[row], m1 = mpart[M_ + row];
    const float l0 = lpart[row], l1 = lpart[M_ + row];
    const float m  = fmaxf(m0, m1);
    const float a0 = __expf(m0 - m), a1 = __expf(m1 - m);
    const float inv = 1.f / (a0 * l0 + a1 * l1);
    f32x4_t o0 = *(const f32x4_t*)&Opart[idx * 4];
    f32x4_t o1 = *(const f32x4_t*)&Opart[(long)M_ * H_ + idx * 4];
    f32x4_t o;
    #pragma unroll
    for (int r = 0; r < 4; ++r) o[r] = (a0 * o0[r] + a1 * o1[r]) * inv;
    *(f32x4_t*)&out[idx * 4] = o;
}

// ---------------------------------------------------------------------------
extern "C" void kernel_launch(void* const* d_in, const int* in_sizes, int n_in,
                              void* d_out, int out_size, void* d_ws, size_t ws_size,
                              hipStream_t stream)
{
    // setup_inputs order: x, Wk, Wq, Wv — all float32
    const float* x  = (const float*)d_in[0];
    const float* Wk = (const float*)d_in[1];
    const float* Wq = (const float*)d_in[2];
    const float* Wv = (const float*)d_in[3];

    // ws: q | k | vT [B][H][T] | WT [3][H][C]  (all bf16)
    //     | Opart [2][B][T][H] f32 | mpart [2][B*T] f32 | lpart [2][B*T] f32
    __bf16* qws = (__bf16*)d_ws;
    __bf16* kws = qws + M_ * H_;
    __bf16* vws = kws + M_ * H_;
    __bf16* WT  = vws + (long)B_ * H_ * T_;
    float*  Opart = (float*)(WT + 3L * H_ * C_);
    float*  mpart = Opart + 2L * M_ * H_;
    float*  lpart = mpart + 2L * M_;
    float*  out = (float*)d_out;

    wt_kernel   <<<dim3(C_ / 8, 3), 128, 0, stream>>>(Wq, Wk, Wv, WT);
    proj_kernel <<<dim3((int)(M_ / 128)), 512, 0, stream>>>(x, WT, qws, kws, vws);
    attn_kernel <<<dim3(512), 512, 0, stream>>>(qws, kws, vws, Opart, mpart, lpart);
    merge_kernel<<<dim3((int)(M_ * H_ / 4 / 256)), 256, 0, stream>>>(Opart, mpart, lpart, out);
}

// Round 13
// 271.603 us; speedup vs baseline: 1.0686x; 1.0040x over previous
//
#include <hip/hip_runtime.h>
#include <hip/hip_bf16.h>

typedef __bf16 bf16x8_t __attribute__((ext_vector_type(8)));
typedef __bf16 bf16x4_t __attribute__((ext_vector_type(4)));
typedef float  f32x4_t  __attribute__((ext_vector_type(4)));

#define MFMA_16x16x32_BF16(A, B, C) __builtin_amdgcn_mfma_f32_16x16x32_bf16((A), (B), (C), 0, 0, 0)

static constexpr int B_ = 16;
static constexpr int T_ = 2048;
static constexpr int C_ = 1024;
static constexpr int H_ = 128;
static constexpr long M_ = (long)B_ * T_;   // 32768 rows

__device__ __forceinline__ void gload_lds16(const void* g, void* l)
{
    __builtin_amdgcn_global_load_lds(
        (const __attribute__((address_space(1))) void*)g,
        (__attribute__((address_space(3))) void*)l, 16, 0, 0);
}

// ---------------------------------------------------------------------------
// W transpose: WT[z][h][c] = bf16(W_z[c][h]).  Flat: WT[n][c], n = z*128+h.
// ---------------------------------------------------------------------------
__global__ __launch_bounds__(128) void wt_kernel(
    const float* __restrict__ Wq, const float* __restrict__ Wk,
    const float* __restrict__ Wv, __bf16* __restrict__ WT)
{
    const int z = blockIdx.y;
    const float* __restrict__ W = (z == 0) ? Wq : (z == 1) ? Wk : Wv;
    const int h  = threadIdx.x;
    const int c0 = blockIdx.x * 8;
    bf16x8_t v;
    #pragma unroll
    for (int j = 0; j < 8; ++j)
        v[j] = (__bf16)W[(c0 + j) * H_ + h];
    *(bf16x8_t*)&WT[((long)z * H_ + h) * C_ + c0] = v;
}

// ---------------------------------------------------------------------------
// Fused projection, v5 build (session-best proj, ~79 us; 7 rewrites all
// plateau here — W-broadcast + x-once tiling pins this shape).
// 128x384 block, grid 256, 8 waves (2m x 4n), wave = 64r x 96c = 4a x 6b
// = 24 MFMA/k-step. 3 LDS buffers, prefetch distance 2, per-step vmcnt(5)
// before the barrier. All staging via global_load_lds (x as fp32, cvt at
// frag build). Swizzles both-sides: x unit^=row&7, W unit^=(row>>1)&3.
// ---------------------------------------------------------------------------
__global__ __launch_bounds__(512, 2) void proj_kernel(
    const float*  __restrict__ x,
    const __bf16* __restrict__ WT,
    __bf16* __restrict__ qo,
    __bf16* __restrict__ ko,
    __bf16* __restrict__ vo)
{
    __shared__ float  XS[3][128 * 32];   // fp32 x tiles, 16 KB each
    __shared__ __bf16 WS[3][384 * 32];   // bf16 W tiles, 24 KB each

    const int tid  = threadIdx.x;
    const int w    = tid >> 6;
    const int lane = tid & 63;
    const int m16  = lane & 15;
    const int quad = lane >> 4;
    const int wm   = w >> 2;             // row-half 0..1 (64 rows)
    const int wn   = w & 3;              // col-quarter 0..3 (6 n-tiles)

    const long r0 = (long)blockIdx.x * 128;

    // staging lane maps (pre-swizzled GLOBAL source, linear LDS dest)
    const int xl_row = lane >> 3;                     // row within 8-row chunk
    const int xl_u   = (lane & 7) ^ xl_row;           // f32 unit (4 floats)
    const int wl_row = lane >> 2;                     // row within 16-row chunk
    const int wl_u   = (lane & 3) ^ ((lane >> 3) & 3);// bf16 unit (8 elems)

    f32x4_t acc[4][6];
    #pragma unroll
    for (int hh = 0; hh < 4; ++hh)
        #pragma unroll
        for (int j = 0; j < 6; ++j) acc[hh][j] = f32x4_t{0, 0, 0, 0};

#define ISSUE(T, BUF)                                                        \
    {                                                                        \
        const int k0_ = (T) * 32;                                            \
        _Pragma("unroll")                                                    \
        for (int ch = 0; ch < 2; ++ch) {                                     \
            const int rb = w * 8 + ch * 64;                                  \
            gload_lds16(&x[(r0 + rb + xl_row) * C_ + k0_ + xl_u * 4],        \
                        &XS[BUF][rb * 32]);                                  \
        }                                                                    \
        _Pragma("unroll")                                                    \
        for (int ch = 0; ch < 3; ++ch) {                                     \
            const int rb = w * 48 + ch * 16;                                 \
            gload_lds16(&WT[(long)(rb + wl_row) * C_ + k0_ + wl_u * 8],      \
                        &WS[BUF][rb * 32]);                                  \
        }                                                                    \
    }

    // ---- prologue: buffers 0 and 1 in flight; wait only for buffer 0 ----
    ISSUE(0, 0);
    ISSUE(1, 1);
    asm volatile("s_waitcnt vmcnt(5)" ::: "memory");
    __builtin_amdgcn_sched_barrier(0);
    __builtin_amdgcn_s_barrier();
    __builtin_amdgcn_sched_barrier(0);

    const int asw = m16 & 7;                           // x unit swizzle
    const int qsw = (quad ^ ((m16 >> 1) & 3)) << 3;    // W bf16-elem offset

    for (int t = 0; t < 32; ++t) {
        const int cur = t % 3;
        if (t + 2 < 32) ISSUE(t + 2, (t + 2) % 3);
        __builtin_amdgcn_sched_barrier(0);

        // a-frags: fp32 -> bf16, swizzled read
        bf16x8_t a[4];
        #pragma unroll
        for (int hh = 0; hh < 4; ++hh) {
            const int row = wm * 64 + hh * 16 + m16;
            f32x4_t lo = *(const f32x4_t*)&XS[cur][row * 32 + (((quad * 2 + 0) ^ asw) << 2)];
            f32x4_t hi = *(const f32x4_t*)&XS[cur][row * 32 + (((quad * 2 + 1) ^ asw) << 2)];
            #pragma unroll
            for (int jj = 0; jj < 4; ++jj) {
                a[hh][jj]     = (__bf16)lo[jj];
                a[hh][4 + jj] = (__bf16)hi[jj];
            }
        }
        // b-frags + 24 MFMAs (b reused x4)
        #pragma unroll
        for (int j = 0; j < 6; ++j) {
            const int row = wn * 96 + j * 16 + m16;
            bf16x8_t b = *(const bf16x8_t*)&WS[cur][row * 32 + qsw];
            #pragma unroll
            for (int hh = 0; hh < 4; ++hh)
                acc[hh][j] = MFMA_16x16x32_BF16(a[hh], b, acc[hh][j]);
        }

        __builtin_amdgcn_sched_barrier(0);
        if (t + 2 < 32) asm volatile("s_waitcnt vmcnt(5)" ::: "memory");
        else            asm volatile("s_waitcnt vmcnt(0)" ::: "memory");
        asm volatile("s_waitcnt lgkmcnt(0)" ::: "memory");
        __builtin_amdgcn_s_barrier();          // publish buf[t+1]; reads done
        __builtin_amdgcn_sched_barrier(0);
    }
#undef ISSUE

    // Epilogue. C/D: col = m16 (n), row = quad*4 + r (m).
    #pragma unroll
    for (int hh = 0; hh < 4; ++hh) {
        const long rbase = r0 + wm * 64 + hh * 16 + quad * 4;
        #pragma unroll
        for (int j = 0; j < 6; ++j) {
            const int nt = wn * 6 + j;
            const int z  = nt >> 3;
            const int h  = (nt & 7) * 16 + m16;
            if (z < 2) {
                __bf16* __restrict__ o = z ? ko : qo;
                #pragma unroll
                for (int r = 0; r < 4; ++r)
                    o[(rbase + r) * H_ + h] = (__bf16)acc[hh][j][r];
            } else {
                long bb = rbase >> 11, tt = rbase & 2047;  // rows stay in batch
                bf16x4_t pk;
                #pragma unroll
                for (int r = 0; r < 4; ++r) pk[r] = (__bf16)acc[hh][j][r];
                *(bf16x4_t*)&vo[bb * (H_ * (long)T_) + h * (long)T_ + tt] = pk;
            }
        }
    }
}

// ---------------------------------------------------------------------------
// Flash attention, split-K=2, QBLK=128, v3: gload_lds K/V staging.
// Round-12 theory: staging was 8 global loads -> VGPR -> 8 ds_writes per
// thread per tile (Common-mistake #1). Now: LINEAR K[64][128] / V[128][64]
// tiles, 4 gload_lds16 per thread, both-sides XOR unit-swizzle (source
// u^=(row&7); fragment read u^=(m16&7)) -> 2-way banks (free, m136).
// LDS 50 KB -> 2 blocks/CU co-resident (grid 512); m114 cross-block
// overlap hides the per-tile barrier drain. T5 setprio(1) around MFMA
// clusters (+4-7% evidenced on attn, m191). Split/merge math unchanged
// (fully-masked tiles self-correct; merge weights kill m=-1e30 halves).
// ---------------------------------------------------------------------------
__global__ __launch_bounds__(512, 2) void attn_kernel(
    const __bf16* __restrict__ q,   // [B][T][H]
    const __bf16* __restrict__ k,   // [B][T][H]
    const __bf16* __restrict__ vT,  // [B][H][T]
    float* __restrict__ Opart,      // [2][B][T][H] fp32, unnormalized
    float* __restrict__ mpart,      // [2][B*T]
    float* __restrict__ lpart)      // [2][B*T]
{
    __shared__ __bf16 KS[64 * 128];     // [krow][h], LINEAR (16 KB)
    __shared__ __bf16 VS[128 * 64];     // [h][t],    LINEAR (16 KB)
    __shared__ __bf16 PS[8][16 * 72];   // per-wave P [q][k], pad 8 (18.4 KB)

    const int bid  = blockIdx.x;
    const int half = bid & 1;
    const int L    = bid >> 1;                    // 0..255
    const int b    = L & 15;
    const int Lh   = L >> 4;                      // 0..15
    const int qb   = (Lh < 8) ? (15 - Lh) : (Lh - 8);  // heavy first, CU-complementary

    const int tid  = threadIdx.x;
    const int w    = tid >> 6;                    // 0..7
    const int lane = tid & 63;
    const int m16  = lane & 15;
    const int quad = lane >> 4;
    const int koff = quad * 8;

    const __bf16* __restrict__ qp = q  + (long)b * T_ * H_;
    const __bf16* __restrict__ kp = k  + (long)b * T_ * H_;
    const __bf16* __restrict__ vp = vT + (long)b * H_ * T_;

    const int q0w = qb * 128 + w * 16;            // wave's q-tile base
    const int qg  = q0w + m16;                    // this lane's q row

    // Q^T B-fragments (lane n=m16=q, k=h)
    bf16x8_t qfr[4];
    #pragma unroll
    for (int s = 0; s < 4; ++s)
        qfr[s] = *(const bf16x8_t*)&qp[(q0w + m16) * H_ + s * 32 + koff];

    f32x4_t acc[8];                               // O^T: row=h, col=q
    #pragma unroll
    for (int i = 0; i < 8; ++i) acc[i] = f32x4_t{0, 0, 0, 0};
    float mrun = -1e30f, lrun = 0.f;

    __bf16* Pb = &PS[w][0];
    const float SC = 0.08838834764831845f;        // 1/sqrt(128)

    // tile range for this half (64-wide tiles)
    const int ntile = 2 * qb + 2;
    const int n0    = qb + 1;
    const int tt0   = half ? n0 : 0;
    const int tt1   = half ? ntile : n0;

    // gload_lds staging lane maps (pre-swizzled GLOBAL source, linear LDS)
    // K chunk ch: LDS bf16 idx = ch*4096 + w*512 + lane*8
    //   -> krow = ch*32 + w*4 + (lane>>4), unit u = lane&15 (16B units)
    const int k_row_in = (lane >> 4);             // + ch*32 + w*4
    const int k_u      = lane & 15;
    // V chunk ch: LDS bf16 idx = ch*4096 + w*512 + lane*8
    //   -> vrow = ch*64 + w*8 + (lane>>3), unit u = lane&7
    const int v_row_in = (lane >> 3);             // + ch*64 + w*8
    const int v_u      = lane & 7;

    const int asw = m16 & 7;                      // fragment-read unit swizzle

    for (int tt = tt0; tt < tt1; ++tt) {
        const int tk0 = tt * 64;
        __syncthreads();                          // prev compute done
        #pragma unroll
        for (int ch = 0; ch < 2; ++ch) {
            const int r  = ch * 32 + w * 4 + k_row_in;
            const int us = k_u ^ (r & 7);         // source-side swizzle
            gload_lds16(&kp[(tk0 + r) * H_ + us * 8], &KS[ch * 4096 + w * 512]);
        }
        #pragma unroll
        for (int ch = 0; ch < 2; ++ch) {
            const int hh = ch * 64 + w * 8 + v_row_in;
            const int us = v_u ^ (hh & 7);
            gload_lds16(&vp[(long)hh * T_ + tk0 + us * 8], &VS[ch * 4096 + w * 512]);
        }
        __syncthreads();                          // tiles ready (drains vmcnt)

        // ---- S^T = K Q^T : 4 S-tiles of 16 k-rows (swizzled K reads) ----
        f32x4_t st[4];
        __builtin_amdgcn_s_setprio(1);
        #pragma unroll
        for (int kt = 0; kt < 4; ++kt) {
            f32x4_t s = f32x4_t{0, 0, 0, 0};
            #pragma unroll
            for (int sI = 0; sI < 4; ++sI) {
                const int u = (sI * 4 + quad) ^ asw;
                bf16x8_t kf = *(const bf16x8_t*)&KS[(kt * 16 + m16) * 128 + u * 8];
                s = MFMA_16x16x32_BF16(kf, qfr[sI], s);
            }
            st[kt] = s;
        }
        __builtin_amdgcn_s_setprio(0);

        // ---- scale (+ causal mask only on boundary tiles, wave-uniform) ----
        float vv[4][4];
        if (tk0 + 63 <= q0w) {                    // fully unmasked
            #pragma unroll
            for (int kt = 0; kt < 4; ++kt)
                #pragma unroll
                for (int r = 0; r < 4; ++r)
                    vv[kt][r] = st[kt][r] * SC;
        } else {
            #pragma unroll
            for (int kt = 0; kt < 4; ++kt)
                #pragma unroll
                for (int r = 0; r < 4; ++r) {
                    int kg = tk0 + kt * 16 + quad * 4 + r;
                    vv[kt][r] = (kg <= qg) ? st[kt][r] * SC : -1e30f;
                }
        }

        float mloc = -1e30f;
        #pragma unroll
        for (int kt = 0; kt < 4; ++kt)
            #pragma unroll
            for (int r = 0; r < 4; ++r)
                mloc = fmaxf(mloc, vv[kt][r]);
        mloc = fmaxf(mloc, __shfl_xor(mloc, 16, 64));
        mloc = fmaxf(mloc, __shfl_xor(mloc, 32, 64));

        float mnew = fmaxf(mrun, mloc);
        float al   = __expf(mrun - mnew);
        float psum = 0.f;
        #pragma unroll
        for (int kt = 0; kt < 4; ++kt) {
            bf16x4_t pk;
            #pragma unroll
            for (int r = 0; r < 4; ++r) {
                float p = __expf(vv[kt][r] - mnew);
                psum += p;
                pk[r] = (__bf16)p;
            }
            *(bf16x4_t*)&Pb[m16 * 72 + kt * 16 + quad * 4] = pk;
        }
        psum += __shfl_xor(psum, 16, 64);
        psum += __shfl_xor(psum, 32, 64);
        mrun = mnew;
        lrun = lrun * al + psum;

        #pragma unroll
        for (int i = 0; i < 8; ++i)
            #pragma unroll
            for (int r = 0; r < 4; ++r)
                acc[i][r] *= al;

        // ---- O^T += V^T P^T : two K=32 halves (swizzled V reads) ----
        __builtin_amdgcn_s_setprio(1);
        #pragma unroll
        for (int hf = 0; hf < 2; ++hf) {
            bf16x8_t pa = *(const bf16x8_t*)&Pb[m16 * 72 + hf * 32 + koff];
            #pragma unroll
            for (int i = 0; i < 8; ++i) {
                const int u = (hf * 4 + quad) ^ asw;
                bf16x8_t vf = *(const bf16x8_t*)&VS[(i * 16 + m16) * 64 + u * 8];
                acc[i] = MFMA_16x16x32_BF16(vf, pa, acc[i]);
            }
        }
        __builtin_amdgcn_s_setprio(0);
    }

    // ---- epilogue: UNNORMALIZED O + per-row (m, l) ----
    float* __restrict__ ob = Opart + ((long)half * B_ + b) * T_ * H_;
    #pragma unroll
    for (int i = 0; i < 8; ++i)
        *(f32x4_t*)&ob[(q0w + m16) * H_ + i * 16 + quad * 4] = acc[i];
    if (quad == 0) {
        const long rix = (long)half * M_ + (long)b * T_ + q0w + m16;
        mpart[rix] = mrun;
        lpart[rix] = lrun;
    }
}

// ---------------------------------------------------------------------------
// Merge the 2 split-K partials: out = sum_i exp(mi-m) Oi / sum_i exp(mi-m) li
// ---------------------------------------------------------------------------
__global__ __launch_bounds__(256) void merge_kernel(
    const float* __restrict__ Opart, const float* __restrict__ mpart,
    const float* __restrict__ lpart, float* __restrict__ out)
{
    const long idx = (long)blockIdx.x * 256 + threadIdx.x;   // f32x4 index
    const long row = idx >> 5;                               // global q-row
    const float m0 = mpart[row], m1 = mpart[M_ + row];
    const float l0 = lpart[row], l1 = lpart[M_ + row];
    const float m  = fmaxf(m0, m1);
    const float a0 = __expf(m0 - m), a1 = __expf(m1 - m);
    const float inv = 1.f / (a0 * l0 + a1 * l1);
    f32x4_t o0 = *(const f32x4_t*)&Opart[idx * 4];
    f32x4_t o1 = *(const f32x4_t*)&Opart[(long)M_ * H_ + idx * 4];
    f32x4_t o;
    #pragma unroll
    for (int r = 0; r < 4; ++r) o[r] = (a0 * o0[r] + a1 * o1[r]) * inv;
    *(f32x4_t*)&out[idx * 4] = o;
}

// ---------------------------------------------------------------------------
extern "C" void kernel_launch(void* const* d_in, const int* in_sizes, int n_in,
                              void* d_out, int out_size, void* d_ws, size_t ws_size,
                              hipStream_t stream)
{
    // setup_inputs order: x, Wk, Wq, Wv — all float32
    const float* x  = (const float*)d_in[0];
    const float* Wk = (const float*)d_in[1];
    const float* Wq = (const float*)d_in[2];
    const float* Wv = (const float*)d_in[3];

    // ws: q | k | vT [B][H][T] | WT [3][H][C]  (all bf16)
    //     | Opart [2][B][T][H] f32 | mpart [2][B*T] f32 | lpart [2][B*T] f32
    __bf16* qws = (__bf16*)d_ws;
    __bf16* kws = qws + M_ * H_;
    __bf16* vws = kws + M_ * H_;
    __bf16* WT  = vws + (long)B_ * H_ * T_;
    float*  Opart = (float*)(WT + 3L * H_ * C_);
    float*  mpart = Opart + 2L * M_ * H_;
    float*  lpart = mpart + 2L * M_;
    float*  out = (float*)d_out;

    wt_kernel   <<<dim3(C_ / 8, 3), 128, 0, stream>>>(Wq, Wk, Wv, WT);
    proj_kernel <<<dim3((int)(M_ / 128)), 512, 0, stream>>>(x, WT, qws, kws, vws);
    attn_kernel <<<dim3(512), 512, 0, stream>>>(qws, kws, vws, Opart, mpart, lpart);
    merge_kernel<<<dim3((int)(M_ * H_ / 4 / 256)), 256, 0, stream>>>(Opart, mpart, lpart, out);
}